// Round 4
// baseline (700.987 us; speedup 1.0000x reference)
//
#include <hip/hip_runtime.h>

typedef _Float16 f16;
typedef __attribute__((ext_vector_type(8))) _Float16 f16x8;
typedef __attribute__((ext_vector_type(4))) _Float16 f16x4;
typedef __attribute__((ext_vector_type(4))) float    f32x4;

#define MFMA(a,b,c) __builtin_amdgcn_mfma_f32_16x16x32_f16(a,b,c,0,0,0)

// problem constants
constexpr int Bc = 2, Nc = 65536, Cc = 256, Hc = 8;
constexpr int CHUNK = 512;                 // tokens per block: 4 m0-tiles of 128
constexpr int LDX = 72;                    // staging stride (f16)
constexpr int LDT = 136;                   // fxT/wT stride (f16), aliased into staging buffers

// ---- workspace layout (bytes) ----
// 0      : Tg    float[16*4096] (262144)
// 262144 : normg float[16*64]   (4096)
// 266240 : WC    f16[8*128*256] (524288)  [h][n][k]; n 0..63 = Wfx cols, 64..127 = Wxs = Wx_h@Ws
// 790528 : bsp   float[8*64]    (2048)    folded slice bias: bx_h@Ws + bsl

__device__ __forceinline__ f32x4 splat4(float v) { f32x4 r; r.x=v; r.y=v; r.z=v; r.w=v; return r; }
__device__ __forceinline__ f16x8 pack8(float4 a, float4 b) {
  f16x8 r = { (f16)a.x,(f16)a.y,(f16)a.z,(f16)a.w,(f16)b.x,(f16)b.y,(f16)b.z,(f16)b.w };
  return r;
}

// prep: 97 blocks.
//  b 0..31 : LDS-tiled transpose of Wfx -> WC fx rows
//  b 32..95: Wxs_h = Wx_h @ Ws (64 blocks)
//  b 96    : bsp
__global__ void prep_a(const float* __restrict__ Wx, const float* __restrict__ Wfx,
                       const float* __restrict__ Wsl, const float* __restrict__ bx,
                       const float* __restrict__ bsl, f16* __restrict__ WC,
                       float* __restrict__ bsp) {
  __shared__ float tile[64][72];
  const int b = blockIdx.x, t = threadIdx.x;
  if (b < 32) {                            // transpose Wfx tile (k0..+64) x (c0..+64)
    const int k0 = (b & 3) * 64, c0 = (b >> 2) * 64;
    const int r = t >> 4, c4 = (t & 15) * 4;
    #pragma unroll
    for (int i = 0; i < 4; ++i) {
      float4 v = *(const float4*)&Wfx[(size_t)(k0 + r + i*16)*512 + c0 + c4];
      tile[r + i*16][c4] = v.x; tile[r + i*16][c4+1] = v.y;
      tile[r + i*16][c4+2] = v.z; tile[r + i*16][c4+3] = v.w;
    }
    __syncthreads();
    const int cl = t >> 2, kq = t & 3;
    const int col = c0 + cl, h = col >> 6, n = col & 63;
    f16 tmp[16];
    #pragma unroll
    for (int j = 0; j < 16; ++j) tmp[j] = (f16)tile[kq*16 + j][cl];
    f16* dst = WC + (size_t)(h*128 + n)*256 + k0 + kq*16;
    *(f16x8*)dst       = *(f16x8*)&tmp[0];
    *(f16x8*)(dst + 8) = *(f16x8*)&tmp[8];
  } else if (b < 96) {                     // Wxs rows
    const int bb = b - 32;
    const int h = bb >> 3, k0 = (bb & 7) * 32;
    const int k = t & 31, sq = t >> 5;     // 8 s-values per thread
    float accs[8];
    #pragma unroll
    for (int j = 0; j < 8; ++j) accs[j] = 0.f;
    for (int d = 0; d < 64; ++d) {
      float a = Wx[(size_t)(k0 + k)*512 + h*64 + d];
      #pragma unroll
      for (int j = 0; j < 8; ++j) accs[j] += a * Wsl[d*64 + sq*8 + j];
    }
    #pragma unroll
    for (int j = 0; j < 8; ++j)
      WC[(size_t)(h*128 + 64 + sq*8 + j)*256 + k0 + k] = (f16)accs[j];
  } else {                                 // bsp[h][s]
    for (int u = t; u < 512; u += 256) {
      int h = u >> 6, s = u & 63;
      float a = bsl[s];
      for (int d = 0; d < 64; ++d) a += bx[h*64 + d] * Wsl[d*64 + s];
      bsp[h*64 + s] = a;
    }
  }
}

__global__ __launch_bounds__(256, 4)
void fused_main(const float* __restrict__ x,   const float* __restrict__ bfx,
                const float* __restrict__ bsp, const float* __restrict__ temp,
                const f16* __restrict__ WC,    float* __restrict__ Tg,
                float* __restrict__ normg) {
  // two 18432-B buffers; staging [128][LDX] aliased with transposed [64][LDT]
  __shared__ alignas(16) char smem[2 * 128 * LDX * 2];   // 36864 B -> 4 blocks/CU
  f16* sm_x   = (f16*)smem;                // x staging    | alias: fx^T [d64][tok128]
  f16* sm_w   = (f16*)(smem + 128*LDX*2);  // W staging    | alias: w^T  [s64][tok128]
  f16* sm_fxT = sm_x;
  f16* sm_wT  = sm_w;

  // XCD swizzle: all 8 heads of a chunk on one XCD
  const int j    = blockIdx.x;
  const int xcd  = j & 7, slot = j >> 3;
  const int chunk = xcd * 32 + (slot >> 3);
  const int h     = slot & 7;

  const int tid = threadIdx.x;
  const int wv = tid >> 6, lane = tid & 63, quad = lane >> 4, ln = lane & 15;
  const int wm = wv >> 1, wn = wv & 1;
  const long tokBase = (long)chunk * CHUNK;
  const int b  = (int)(tokBase >> 16);
  const int bh = b * Hc + h;

  const float tc = fminf(fmaxf(temp[h], 0.5f), 5.0f);
  const float k2 = 1.44269504f / tc;

  float bv[4];
  {
    const float* bb = (wn == 0) ? (bfx + h*64) : (bsp + h*64);
    #pragma unroll
    for (int nt = 0; nt < 4; ++nt) bv[nt] = bb[nt*16 + ln];
  }

  f32x4 Tacc[2][2];
  #pragma unroll
  for (int i = 0; i < 2; ++i) { Tacc[i][0] = splat4(0.f); Tacc[i][1] = splat4(0.f); }
  float nacc[4] = {0.f, 0.f, 0.f, 0.f};
  const int ci = wv >> 1, cj = wv & 1;

  const f16* WCh = WC + (size_t)h * 128 * 256;

  const int r0 = tid >> 2, seg = tid & 3;
  const int wrow = tid >> 1, whalf = tid & 1;

  float4 xr[8]; f16x8 wr[4];
  auto loadx = [&](int m0, int kb) {
    const float* p = x + (tokBase + (long)m0*128 + r0)*Cc + kb*64 + seg*16;
    xr[0] = *(const float4*)p;        xr[1] = *(const float4*)(p + 4);
    xr[2] = *(const float4*)(p + 8);  xr[3] = *(const float4*)(p + 12);
    p += 64 * Cc;
    xr[4] = *(const float4*)p;        xr[5] = *(const float4*)(p + 4);
    xr[6] = *(const float4*)(p + 8);  xr[7] = *(const float4*)(p + 12);
  };
  auto loadw = [&](int kb) {
    const f16* p = WCh + wrow*256 + kb*64 + whalf*32;
    wr[0] = *(const f16x8*)p;         wr[1] = *(const f16x8*)(p + 8);
    wr[2] = *(const f16x8*)(p + 16);  wr[3] = *(const f16x8*)(p + 24);
  };

  loadx(0, 0); loadw(0);

  for (int m0 = 0; m0 < 4; ++m0) {
    // ---------- Phase A: [fx | sp] = x_tile(128x256) @ WC_h(256x128) ----------
    f32x4 acc[4][4];
    #pragma unroll
    for (int mt = 0; mt < 4; ++mt)
      #pragma unroll
      for (int nt = 0; nt < 4; ++nt) acc[mt][nt] = splat4(bv[nt]);

    for (int kb = 0; kb < 4; ++kb) {
      __syncthreads();                     // prev phase-C / MFMA reads done before overwrite
      *(f16x8*)&sm_x[r0*LDX + seg*16]          = pack8(xr[0], xr[1]);
      *(f16x8*)&sm_x[r0*LDX + seg*16 + 8]      = pack8(xr[2], xr[3]);
      *(f16x8*)&sm_x[(r0+64)*LDX + seg*16]     = pack8(xr[4], xr[5]);
      *(f16x8*)&sm_x[(r0+64)*LDX + seg*16 + 8] = pack8(xr[6], xr[7]);
      *(f16x8*)&sm_w[wrow*LDX + whalf*32]      = wr[0];
      *(f16x8*)&sm_w[wrow*LDX + whalf*32 +  8] = wr[1];
      *(f16x8*)&sm_w[wrow*LDX + whalf*32 + 16] = wr[2];
      *(f16x8*)&sm_w[wrow*LDX + whalf*32 + 24] = wr[3];
      { int nkb = kb + 1, nm0 = m0;
        if (nkb == 4) { nkb = 0; ++nm0; }
        if (nm0 < 4) { loadx(nm0, nkb); loadw(nkb); } }
      __syncthreads();
      #pragma unroll
      for (int ks = 0; ks < 2; ++ks) {
        f16x8 af[4], bf[4];
        #pragma unroll
        for (int mt = 0; mt < 4; ++mt)
          af[mt] = *(const f16x8*)&sm_x[(wm*64 + mt*16 + ln)*LDX + ks*32 + quad*8];
        #pragma unroll
        for (int nt = 0; nt < 4; ++nt)
          bf[nt] = *(const f16x8*)&sm_w[(wn*64 + nt*16 + ln)*LDX + ks*32 + quad*8];
        #pragma unroll
        for (int mt = 0; mt < 4; ++mt)
          #pragma unroll
          for (int nt = 0; nt < 4; ++nt)
            acc[mt][nt] = MFMA(af[mt], bf[nt], acc[mt][nt]);
      }
    }
    __syncthreads();                       // all phase-A LDS reads done before alias rewrite

    // ---------- epilogue into aliased buffers ----------
    if (wn == 0) {
      #pragma unroll
      for (int mt = 0; mt < 4; ++mt)
        #pragma unroll
        for (int nt = 0; nt < 4; ++nt) {
          f16x4 v = { (f16)acc[mt][nt][0], (f16)acc[mt][nt][1],
                      (f16)acc[mt][nt][2], (f16)acc[mt][nt][3] };
          *(f16x4*)&sm_fxT[(nt*16 + ln)*LDT + wm*64 + mt*16 + quad*4] = v;
        }
    } else {
      #pragma unroll
      for (int mt = 0; mt < 4; ++mt) {
        float e[4][4], wout[4][4];
        #pragma unroll
        for (int nt = 0; nt < 4; ++nt)
          #pragma unroll
          for (int rg = 0; rg < 4; ++rg)
            e[nt][rg] = exp2f(acc[mt][nt][rg] * k2);   // no max-sub: logits bounded
        #pragma unroll
        for (int rg = 0; rg < 4; ++rg) {
          float rs = e[0][rg] + e[1][rg] + e[2][rg] + e[3][rg];
          #pragma unroll
          for (int dd = 1; dd < 16; dd <<= 1) rs += __shfl_xor(rs, dd, 64);
          float inv = 1.0f / rs;
          #pragma unroll
          for (int nt = 0; nt < 4; ++nt) {
            wout[nt][rg] = e[nt][rg] * inv;
            nacc[nt] += wout[nt][rg];
          }
        }
        #pragma unroll
        for (int nt = 0; nt < 4; ++nt) {
          f16x4 v = { (f16)wout[nt][0], (f16)wout[nt][1],
                      (f16)wout[nt][2], (f16)wout[nt][3] };
          *(f16x4*)&sm_wT[(nt*16 + ln)*LDT + wm*64 + mt*16 + quad*4] = v;
        }
      }
    }
    __syncthreads();

    // ---------- Phase C: T[s][d] += w^T @ fx, K=128 ----------
    #pragma unroll
    for (int ks = 0; ks < 4; ++ks) {
      f16x8 a0 = *(const f16x8*)&sm_wT [(ci*32 +      ln)*LDT + ks*32 + quad*8];
      f16x8 a1 = *(const f16x8*)&sm_wT [(ci*32 + 16 + ln)*LDT + ks*32 + quad*8];
      f16x8 b0 = *(const f16x8*)&sm_fxT[(cj*32 +      ln)*LDT + ks*32 + quad*8];
      f16x8 b1 = *(const f16x8*)&sm_fxT[(cj*32 + 16 + ln)*LDT + ks*32 + quad*8];
      Tacc[0][0] = MFMA(a0, b0, Tacc[0][0]);
      Tacc[0][1] = MFMA(a0, b1, Tacc[0][1]);
      Tacc[1][0] = MFMA(a1, b0, Tacc[1][0]);
      Tacc[1][1] = MFMA(a1, b1, Tacc[1][1]);
    }
    // next m0's kb=0 barrier orders these reads vs staging rewrites
  }

  // ---------- flush ----------
  float* Tb = Tg + bh * 4096;
  #pragma unroll
  for (int mt2 = 0; mt2 < 2; ++mt2)
    #pragma unroll
    for (int nt2 = 0; nt2 < 2; ++nt2)
      #pragma unroll
      for (int rg = 0; rg < 4; ++rg) {
        int s = ci*32 + mt2*16 + quad*4 + rg;
        int d = cj*32 + nt2*16 + ln;
        atomicAdd(&Tb[s*64 + d], Tacc[mt2][nt2][rg]);
      }
  if (wn == 1) {
    #pragma unroll
    for (int nt = 0; nt < 4; ++nt) {
      float v = nacc[nt];
      v += __shfl_xor(v, 16, 64);
      v += __shfl_xor(v, 32, 64);
      if (lane < 16) atomicAdd(&normg[bh*64 + nt*16 + ln], v);
    }
  }
}

__global__ void finalize(const float* __restrict__ Tg, const float* __restrict__ normg,
                         float* __restrict__ out) {
  int i = blockIdx.x * 256 + threadIdx.x;
  out[i] = Tg[i] / (normg[i >> 6] + 0.01f);
}

extern "C" void kernel_launch(void* const* d_in, const int* in_sizes, int n_in,
                              void* d_out, int out_size, void* d_ws, size_t ws_size,
                              hipStream_t stream) {
  const float* x    = (const float*)d_in[0];
  const float* Wx   = (const float*)d_in[1];
  const float* bx   = (const float*)d_in[2];
  const float* Wfx  = (const float*)d_in[3];
  const float* bfx  = (const float*)d_in[4];
  const float* Wsl  = (const float*)d_in[5];
  const float* bsl  = (const float*)d_in[6];
  const float* temp = (const float*)d_in[7];
  float* out = (float*)d_out;

  float* Tg    = (float*)d_ws;
  float* normg = Tg + 16 * 4096;
  f16*   WC    = (f16*)((char*)d_ws + 266240);
  float* bsp   = (float*)((char*)d_ws + 790528);

  hipMemsetAsync(d_ws, 0, 266240, stream);       // zero Tg + normg
  prep_a    <<<97, 256, 0, stream>>>(Wx, Wfx, Wsl, bx, bsl, WC, bsp);
  fused_main<<<2048, 256, 0, stream>>>(x, bfx, bsp, temp, WC, Tg, normg);
  finalize  <<<256, 256, 0, stream>>>(Tg, normg, out);
}

// Round 5
// 346.416 us; speedup vs baseline: 2.0235x; 2.0235x over previous
//
#include <hip/hip_runtime.h>

typedef _Float16 f16;
typedef __attribute__((ext_vector_type(8))) _Float16 f16x8;
typedef __attribute__((ext_vector_type(4))) _Float16 f16x4;
typedef __attribute__((ext_vector_type(4))) float    f32x4;

#define MFMA(a,b,c) __builtin_amdgcn_mfma_f32_16x16x32_f16(a,b,c,0,0,0)

// problem constants
constexpr int Bc = 2, Nc = 65536, Cc = 256, Hc = 8;
constexpr int CHUNK = 512;                 // tokens per block: 4 m0-tiles of 128
constexpr int LDX = 72;                    // staging stride (f16)
constexpr int LDT = 136;                   // fxT/wT stride (f16), aliased into staging buffers

// ---- workspace layout (bytes) ----
// 0      : Tg    float[16*4096] (262144)
// 262144 : normg float[16*64]   (4096)
// 266240 : WC    f16[8*128*256] (524288)  [h][n][k]; n 0..63 = Wfx cols, 64..127 = Wxs = Wx_h@Ws
// 790528 : bsp   float[8*64]    (2048)    folded slice bias: bx_h@Ws + bsl

__device__ __forceinline__ f32x4 splat4(float v) { f32x4 r; r.x=v; r.y=v; r.z=v; r.w=v; return r; }
__device__ __forceinline__ f16x8 pack8(float4 a, float4 b) {
  f16x8 r = { (f16)a.x,(f16)a.y,(f16)a.z,(f16)a.w,(f16)b.x,(f16)b.y,(f16)b.z,(f16)b.w };
  return r;
}

// prep: 97 blocks.
__global__ void prep_a(const float* __restrict__ Wx, const float* __restrict__ Wfx,
                       const float* __restrict__ Wsl, const float* __restrict__ bx,
                       const float* __restrict__ bsl, f16* __restrict__ WC,
                       float* __restrict__ bsp) {
  __shared__ float tile[64][72];
  const int b = blockIdx.x, t = threadIdx.x;
  if (b < 32) {                            // transpose Wfx tile (k0..+64) x (c0..+64)
    const int k0 = (b & 3) * 64, c0 = (b >> 2) * 64;
    const int r = t >> 4, c4 = (t & 15) * 4;
    #pragma unroll
    for (int i = 0; i < 4; ++i) {
      float4 v = *(const float4*)&Wfx[(size_t)(k0 + r + i*16)*512 + c0 + c4];
      tile[r + i*16][c4] = v.x; tile[r + i*16][c4+1] = v.y;
      tile[r + i*16][c4+2] = v.z; tile[r + i*16][c4+3] = v.w;
    }
    __syncthreads();
    const int cl = t >> 2, kq = t & 3;
    const int col = c0 + cl, h = col >> 6, n = col & 63;
    f16 tmp[16];
    #pragma unroll
    for (int j = 0; j < 16; ++j) tmp[j] = (f16)tile[kq*16 + j][cl];
    f16* dst = WC + (size_t)(h*128 + n)*256 + k0 + kq*16;
    *(f16x8*)dst       = *(f16x8*)&tmp[0];
    *(f16x8*)(dst + 8) = *(f16x8*)&tmp[8];
  } else if (b < 96) {                     // Wxs rows
    const int bb = b - 32;
    const int h = bb >> 3, k0 = (bb & 7) * 32;
    const int k = t & 31, sq = t >> 5;     // 8 s-values per thread
    float accs[8];
    #pragma unroll
    for (int j = 0; j < 8; ++j) accs[j] = 0.f;
    for (int d = 0; d < 64; ++d) {
      float a = Wx[(size_t)(k0 + k)*512 + h*64 + d];
      #pragma unroll
      for (int j = 0; j < 8; ++j) accs[j] += a * Wsl[d*64 + sq*8 + j];
    }
    #pragma unroll
    for (int j = 0; j < 8; ++j)
      WC[(size_t)(h*128 + 64 + sq*8 + j)*256 + k0 + k] = (f16)accs[j];
  } else {                                 // bsp[h][s]
    for (int u = t; u < 512; u += 256) {
      int h = u >> 6, s = u & 63;
      float a = bsl[s];
      for (int d = 0; d < 64; ++d) a += bx[h*64 + d] * Wsl[d*64 + s];
      bsp[h*64 + s] = a;
    }
  }
}

// (256,2): empirically the arg-2 cap is VGPR<=512/(2*arg2); (256,4) forced 64 VGPR
// and spilled ~1.1 GB to scratch (round 4). 112 VGPR still gives 4 waves/SIMD;
// LDS 36864 B allows 4 blocks/CU.
__global__ __launch_bounds__(256, 2)
void fused_main(const float* __restrict__ x,   const float* __restrict__ bfx,
                const float* __restrict__ bsp, const float* __restrict__ temp,
                const f16* __restrict__ WC,    float* __restrict__ Tg,
                float* __restrict__ normg) {
  // two 18432-B buffers; staging [128][LDX] aliased with transposed [64][LDT]
  __shared__ alignas(16) char smem[2 * 128 * LDX * 2];   // 36864 B
  f16* sm_x   = (f16*)smem;                // x staging    | alias: fx^T [d64][tok128]
  f16* sm_w   = (f16*)(smem + 128*LDX*2);  // W staging    | alias: w^T  [s64][tok128]
  f16* sm_fxT = sm_x;
  f16* sm_wT  = sm_w;

  // XCD swizzle: all 8 heads of a chunk on one XCD
  const int j    = blockIdx.x;
  const int xcd  = j & 7, slot = j >> 3;
  const int chunk = xcd * 32 + (slot >> 3);
  const int h     = slot & 7;

  const int tid = threadIdx.x;
  const int wv = tid >> 6, lane = tid & 63, quad = lane >> 4, ln = lane & 15;
  const int wm = wv >> 1, wn = wv & 1;
  const long tokBase = (long)chunk * CHUNK;
  const int b  = (int)(tokBase >> 16);
  const int bh = b * Hc + h;

  const float tc = fminf(fmaxf(temp[h], 0.5f), 5.0f);
  const float k2 = 1.44269504f / tc;

  float bv[4];
  {
    const float* bb = (wn == 0) ? (bfx + h*64) : (bsp + h*64);
    #pragma unroll
    for (int nt = 0; nt < 4; ++nt) bv[nt] = bb[nt*16 + ln];
  }

  f32x4 Tacc[2][2];
  #pragma unroll
  for (int i = 0; i < 2; ++i) { Tacc[i][0] = splat4(0.f); Tacc[i][1] = splat4(0.f); }
  float nacc[4] = {0.f, 0.f, 0.f, 0.f};
  const int ci = wv >> 1, cj = wv & 1;

  const f16* WCh = WC + (size_t)h * 128 * 256;

  const int r0 = tid >> 2, seg = tid & 3;
  const int wrow = tid >> 1, whalf = tid & 1;

  float4 xr[8]; f16x8 wr[4];
  auto loadx = [&](int m0, int kb) {
    const float* p = x + (tokBase + (long)m0*128 + r0)*Cc + kb*64 + seg*16;
    xr[0] = *(const float4*)p;        xr[1] = *(const float4*)(p + 4);
    xr[2] = *(const float4*)(p + 8);  xr[3] = *(const float4*)(p + 12);
    p += 64 * Cc;
    xr[4] = *(const float4*)p;        xr[5] = *(const float4*)(p + 4);
    xr[6] = *(const float4*)(p + 8);  xr[7] = *(const float4*)(p + 12);
  };
  auto loadw = [&](int kb) {
    const f16* p = WCh + wrow*256 + kb*64 + whalf*32;
    wr[0] = *(const f16x8*)p;         wr[1] = *(const f16x8*)(p + 8);
    wr[2] = *(const f16x8*)(p + 16);  wr[3] = *(const f16x8*)(p + 24);
  };

  loadx(0, 0); loadw(0);

  for (int m0 = 0; m0 < 4; ++m0) {
    // ---------- Phase A: [fx | sp] = x_tile(128x256) @ WC_h(256x128) ----------
    f32x4 acc[4][4];
    #pragma unroll
    for (int mt = 0; mt < 4; ++mt)
      #pragma unroll
      for (int nt = 0; nt < 4; ++nt) acc[mt][nt] = splat4(bv[nt]);

    for (int kb = 0; kb < 4; ++kb) {
      __syncthreads();                     // prev phase-C / MFMA reads done before overwrite
      *(f16x8*)&sm_x[r0*LDX + seg*16]          = pack8(xr[0], xr[1]);
      *(f16x8*)&sm_x[r0*LDX + seg*16 + 8]      = pack8(xr[2], xr[3]);
      *(f16x8*)&sm_x[(r0+64)*LDX + seg*16]     = pack8(xr[4], xr[5]);
      *(f16x8*)&sm_x[(r0+64)*LDX + seg*16 + 8] = pack8(xr[6], xr[7]);
      *(f16x8*)&sm_w[wrow*LDX + whalf*32]      = wr[0];
      *(f16x8*)&sm_w[wrow*LDX + whalf*32 +  8] = wr[1];
      *(f16x8*)&sm_w[wrow*LDX + whalf*32 + 16] = wr[2];
      *(f16x8*)&sm_w[wrow*LDX + whalf*32 + 24] = wr[3];
      { int nkb = kb + 1, nm0 = m0;
        if (nkb == 4) { nkb = 0; ++nm0; }
        if (nm0 < 4) { loadx(nm0, nkb); loadw(nkb); } }
      __syncthreads();
      #pragma unroll
      for (int ks = 0; ks < 2; ++ks) {
        f16x8 af[4], bf[4];
        #pragma unroll
        for (int mt = 0; mt < 4; ++mt)
          af[mt] = *(const f16x8*)&sm_x[(wm*64 + mt*16 + ln)*LDX + ks*32 + quad*8];
        #pragma unroll
        for (int nt = 0; nt < 4; ++nt)
          bf[nt] = *(const f16x8*)&sm_w[(wn*64 + nt*16 + ln)*LDX + ks*32 + quad*8];
        #pragma unroll
        for (int mt = 0; mt < 4; ++mt)
          #pragma unroll
          for (int nt = 0; nt < 4; ++nt)
            acc[mt][nt] = MFMA(af[mt], bf[nt], acc[mt][nt]);
      }
    }
    __syncthreads();                       // all phase-A LDS reads done before alias rewrite

    // ---------- epilogue into aliased buffers ----------
    if (wn == 0) {
      #pragma unroll
      for (int mt = 0; mt < 4; ++mt)
        #pragma unroll
        for (int nt = 0; nt < 4; ++nt) {
          f16x4 v = { (f16)acc[mt][nt][0], (f16)acc[mt][nt][1],
                      (f16)acc[mt][nt][2], (f16)acc[mt][nt][3] };
          *(f16x4*)&sm_fxT[(nt*16 + ln)*LDT + wm*64 + mt*16 + quad*4] = v;
        }
    } else {
      #pragma unroll
      for (int mt = 0; mt < 4; ++mt) {
        float e[4][4], wout[4][4];
        #pragma unroll
        for (int nt = 0; nt < 4; ++nt)
          #pragma unroll
          for (int rg = 0; rg < 4; ++rg)
            e[nt][rg] = exp2f(acc[mt][nt][rg] * k2);   // no max-sub: logits bounded
        #pragma unroll
        for (int rg = 0; rg < 4; ++rg) {
          float rs = e[0][rg] + e[1][rg] + e[2][rg] + e[3][rg];
          #pragma unroll
          for (int dd = 1; dd < 16; dd <<= 1) rs += __shfl_xor(rs, dd, 64);
          float inv = 1.0f / rs;
          #pragma unroll
          for (int nt = 0; nt < 4; ++nt) {
            wout[nt][rg] = e[nt][rg] * inv;
            nacc[nt] += wout[nt][rg];
          }
        }
        #pragma unroll
        for (int nt = 0; nt < 4; ++nt) {
          f16x4 v = { (f16)wout[nt][0], (f16)wout[nt][1],
                      (f16)wout[nt][2], (f16)wout[nt][3] };
          *(f16x4*)&sm_wT[(nt*16 + ln)*LDT + wm*64 + mt*16 + quad*4] = v;
        }
      }
    }
    __syncthreads();

    // ---------- Phase C: T[s][d] += w^T @ fx, K=128 ----------
    #pragma unroll
    for (int ks = 0; ks < 4; ++ks) {
      f16x8 a0 = *(const f16x8*)&sm_wT [(ci*32 +      ln)*LDT + ks*32 + quad*8];
      f16x8 a1 = *(const f16x8*)&sm_wT [(ci*32 + 16 + ln)*LDT + ks*32 + quad*8];
      f16x8 b0 = *(const f16x8*)&sm_fxT[(cj*32 +      ln)*LDT + ks*32 + quad*8];
      f16x8 b1 = *(const f16x8*)&sm_fxT[(cj*32 + 16 + ln)*LDT + ks*32 + quad*8];
      Tacc[0][0] = MFMA(a0, b0, Tacc[0][0]);
      Tacc[0][1] = MFMA(a0, b1, Tacc[0][1]);
      Tacc[1][0] = MFMA(a1, b0, Tacc[1][0]);
      Tacc[1][1] = MFMA(a1, b1, Tacc[1][1]);
    }
    // next m0's kb=0 barrier orders these reads vs staging rewrites
  }

  // ---------- flush ----------
  float* Tb = Tg + bh * 4096;
  #pragma unroll
  for (int mt2 = 0; mt2 < 2; ++mt2)
    #pragma unroll
    for (int nt2 = 0; nt2 < 2; ++nt2)
      #pragma unroll
      for (int rg = 0; rg < 4; ++rg) {
        int s = ci*32 + mt2*16 + quad*4 + rg;
        int d = cj*32 + nt2*16 + ln;
        atomicAdd(&Tb[s*64 + d], Tacc[mt2][nt2][rg]);
      }
  if (wn == 1) {
    #pragma unroll
    for (int nt = 0; nt < 4; ++nt) {
      float v = nacc[nt];
      v += __shfl_xor(v, 16, 64);
      v += __shfl_xor(v, 32, 64);
      if (lane < 16) atomicAdd(&normg[bh*64 + nt*16 + ln], v);
    }
  }
}

__global__ void finalize(const float* __restrict__ Tg, const float* __restrict__ normg,
                         float* __restrict__ out) {
  int i = blockIdx.x * 256 + threadIdx.x;
  out[i] = Tg[i] / (normg[i >> 6] + 0.01f);
}

extern "C" void kernel_launch(void* const* d_in, const int* in_sizes, int n_in,
                              void* d_out, int out_size, void* d_ws, size_t ws_size,
                              hipStream_t stream) {
  const float* x    = (const float*)d_in[0];
  const float* Wx   = (const float*)d_in[1];
  const float* bx   = (const float*)d_in[2];
  const float* Wfx  = (const float*)d_in[3];
  const float* bfx  = (const float*)d_in[4];
  const float* Wsl  = (const float*)d_in[5];
  const float* bsl  = (const float*)d_in[6];
  const float* temp = (const float*)d_in[7];
  float* out = (float*)d_out;

  float* Tg    = (float*)d_ws;
  float* normg = Tg + 16 * 4096;
  f16*   WC    = (f16*)((char*)d_ws + 266240);
  float* bsp   = (float*)((char*)d_ws + 790528);

  hipMemsetAsync(d_ws, 0, 266240, stream);       // zero Tg + normg
  prep_a    <<<97, 256, 0, stream>>>(Wx, Wfx, Wsl, bx, bsl, WC, bsp);
  fused_main<<<2048, 256, 0, stream>>>(x, bfx, bsp, temp, WC, Tg, normg);
  finalize  <<<256, 256, 0, stream>>>(Tg, normg, out);
}